// Round 20
// baseline (101.584 us; speedup 1.0000x reference)
//
#include <hip/hip_runtime.h>
#include <math.h>

#define BB 8
#define CC 256
#define HH 64
#define WW 64
#define H2 32
#define W2 32
#define NPIX (BB*HH*WW)
#define EPSV 1e-5f

typedef unsigned short ushortT;
using short8  = __attribute__((ext_vector_type(8))) short;
using floatx4 = __attribute__((ext_vector_type(4))) float;

__device__ inline float b2f(ushortT u) {
    unsigned int x = ((unsigned int)u) << 16;
    float f; __builtin_memcpy(&f, &x, 4); return f;
}
__device__ inline ushortT f2b(float f) {
    unsigned int x; __builtin_memcpy(&x, &f, 4);
    unsigned int r = x + 0x7fffu + ((x >> 16) & 1u);   // RNE
    return (ushortT)(r >> 16);
}

// ---------------- K1both v3: guide | x1t transpose | weight prep ---------------- UNCHANGED r18
__global__ __launch_bounds__(256) void k1_both(const float* __restrict__ x2,
        const float* __restrict__ x1, const float* __restrict__ in_w,
        const float* __restrict__ in_b, const float* __restrict__ out_w,
        const float* __restrict__ off_w, const float* __restrict__ mask_w,
        ushortT* __restrict__ guide, ushortT* __restrict__ x1t,
        ushortT* __restrict__ Bf, float* __restrict__ bwout,
        ushortT* __restrict__ Whf) {
    __shared__ __align__(16) float Xs[2 * 64 * 2 * 33];   // 33792 B
    __shared__ __align__(16) ushortT tile[64 * 66];       //  8448 B
    int blk0 = blockIdx.x;
    int t = threadIdx.x;

    if (blk0 >= 4353) {
        int s = (blk0 - 4353) * 256 + t;
        int lane = s & 63;
        int kt = (s >> 6) & 7;
        int nt = s >> 9;
        int n = nt * 16 + (lane & 15);
        int k = kt * 32 + (lane >> 4) * 8;
        short8 o;
        #pragma unroll
        for (int j = 0; j < 8; ++j) {
            float wv = 0.f;
            int kk = k + j;
            if (n < 18)      wv = off_w[kk * 18 + n];
            else if (n < 27) wv = mask_w[kk * 9 + (n - 18)];
            o[j] = (short)f2b(wv);
        }
        *(short8*)(Whf + (size_t)s * 8) = o;
        return;
    }
    if (blk0 >= 4096) {
        float* Wl = Xs;
        int j = blk0 - 4096;
        int n = t;
        Wl[n] = (j < CC) ? in_w[(size_t)j * CC + n] : in_b[n];
        __syncthreads();
        float acc = 0.f;
        #pragma unroll 8
        for (int k = 0; k < CC; ++k)
            acc = fmaf(Wl[k], out_w[(size_t)k * CC + n], acc);
        if (j < CC) {
            int lane = (((j >> 3) & 3) << 4) | (n & 15);
            size_t idx = ((size_t)(((n >> 4) * 8 + (j >> 5)) * 64 + lane)) * 8 + (j & 7);
            Bf[idx] = f2b(acc);
        } else {
            bwout[n] = acc;
        }
        return;
    }

    if (blk0 < 2048) {
        int c0 = (blk0 & 3) * 64;
        int y  = (blk0 >> 2) & 63;
        int b  = blk0 >> 8;
        int bb = b & 3;
        float sy = 0.5f * y - 0.25f;
        float fy0 = floorf(sy);
        float wy = sy - fy0;
        int jy0 = (int)fy0;
        int iy0 = max(0, min(H2 - 1, jy0));
        int iy1 = max(0, min(H2 - 1, jy0 + 1));
        #pragma unroll
        for (int i = 0; i < 8; ++i) {
            int e = t + i * 256;
            int q = e >> 10, ch = (e >> 4) & 63, r = (e >> 3) & 1, xg = (e & 7) * 4;
            int iy = r ? iy1 : iy0;
            float4 v = *(const float4*)(x2 +
                (size_t)(((bb + 4 * q) * CC + c0 + ch) * H2 + iy) * W2 + xg);
            float* dst = Xs + (size_t)((q * 64 + ch) * 2 + r) * 33 + xg;
            dst[0] = v.x; dst[1] = v.y; dst[2] = v.z; dst[3] = v.w;
        }
        __syncthreads();
        int x = t & 63, cl = t >> 6;
        float sx = 0.5f * x - 0.25f;
        float fx0 = floorf(sx);
        float wx = sx - fx0;
        int jx0 = (int)fx0;
        int ix0 = max(0, min(W2 - 1, jx0));
        int ix1 = max(0, min(W2 - 1, jx0 + 1));
        float w00 = (1.f - wy) * (1.f - wx), w01 = (1.f - wy) * wx;
        float w10 = wy * (1.f - wx), w11 = wy * wx;
        #pragma unroll
        for (int it = 0; it < 16; ++it) {
            int c = cl + it * 4;
            const float* a  = Xs + (size_t)(c * 2) * 33;
            const float* bq = Xs + (size_t)((64 + c) * 2) * 33;
            float v1 = w00 * a[ix0]  + w01 * a[ix1]  + w10 * a[33 + ix0]  + w11 * a[33 + ix1];
            float v2 = w00 * bq[ix0] + w01 * bq[ix1] + w10 * bq[33 + ix0] + w11 * bq[33 + ix1];
            tile[x * 66 + c] = f2b(fabsf(v1 - v2));
        }
        __syncthreads();
        #pragma unroll
        for (int i = 0; i < 2; ++i) {
            int e = t + i * 256;
            int px = e >> 3, oct = e & 7;
            uint4 o;
            o.x = *(const unsigned int*)(&tile[px * 66 + oct * 8 + 0]);
            o.y = *(const unsigned int*)(&tile[px * 66 + oct * 8 + 2]);
            o.z = *(const unsigned int*)(&tile[px * 66 + oct * 8 + 4]);
            o.w = *(const unsigned int*)(&tile[px * 66 + oct * 8 + 6]);
            *(uint4*)(guide + (size_t)((b * HH + y) * WW + px) * CC + c0 + oct * 8) = o;
        }
    } else {
        int blk = blk0 - 2048;
        int c0 = (blk & 3) * 64;
        int y  = (blk >> 2) & 63;
        int b  = blk >> 8;
        #pragma unroll
        for (int i = 0; i < 4; ++i) {
            int e = t + i * 256;
            int ch = e >> 4, xq = (e & 15) * 4;
            float4 v = *(const float4*)(x1 + (size_t)((b * CC + c0 + ch) * HH + y) * WW + xq);
            tile[(xq + 0) * 66 + ch] = f2b(v.x);
            tile[(xq + 1) * 66 + ch] = f2b(v.y);
            tile[(xq + 2) * 66 + ch] = f2b(v.z);
            tile[(xq + 3) * 66 + ch] = f2b(v.w);
        }
        __syncthreads();
        #pragma unroll
        for (int i = 0; i < 2; ++i) {
            int e = t + i * 256;
            int px = e >> 3, oct = e & 7;
            uint4 o;
            o.x = *(const unsigned int*)(&tile[px * 66 + oct * 8 + 0]);
            o.y = *(const unsigned int*)(&tile[px * 66 + oct * 8 + 2]);
            o.z = *(const unsigned int*)(&tile[px * 66 + oct * 8 + 4]);
            o.w = *(const unsigned int*)(&tile[px * 66 + oct * 8 + 6]);
            *(uint4*)(x1t + (size_t)((b * HH + y) * WW + px) * CC + c0 + oct * 8) = o;
        }
    }
}

// ---------------- K2ab: dwconv3x3 + LN + GELU (LDS feat) + MFMA heads + softmax -------- r14
__global__ __launch_bounds__(512, 4) void k2ab(const ushortT* __restrict__ guide,
        const float* __restrict__ dw_w, const float* __restrict__ dw_b,
        const float* __restrict__ ln_g, const float* __restrict__ ln_b,
        const ushortT* __restrict__ Whf, const float* __restrict__ off_b,
        const float* __restrict__ mask_b, float* __restrict__ offmask) {
    __shared__ __align__(16) short sfeat[32 * 264];
    __shared__ float O[32 * 36];
    int t = threadIdx.x;
    int blk = ((blockIdx.x & 7) << 7) | (blockIdx.x >> 3);
    int b = blk >> 7, y = (blk >> 1) & 63, xh = (blk & 1) * 32;
    int lane = t & 63, w = t >> 6;
    int cl = lane & 15, rg = lane >> 4;

    {
        int pxl = t >> 4, s = t & 15;
        int c0 = s * 16;
        int xg = xh + pxl;
        float f[16];
        #pragma unroll
        for (int q = 0; q < 4; ++q) {
            float4 d = *(const float4*)(dw_b + c0 + q * 4);
            f[q*4+0]=d.x; f[q*4+1]=d.y; f[q*4+2]=d.z; f[q*4+3]=d.w;
        }
        #pragma unroll
        for (int tap = 0; tap < 9; ++tap) {
            int dy = tap / 3 - 1, dxx = tap % 3 - 1;
            int yy = y + dy, xx = xg + dxx;
            if (yy >= 0 && yy < HH && xx >= 0 && xx < WW) {
                const ushortT* gp = guide + (size_t)((b * HH + yy) * WW + xx) * CC + c0;
                #pragma unroll
                for (int q = 0; q < 2; ++q) {
                    short8 v = *(const short8*)(gp + q * 8);
                    float4 w0 = *(const float4*)(dw_w + tap * CC + c0 + q * 8);
                    float4 w1 = *(const float4*)(dw_w + tap * CC + c0 + q * 8 + 4);
                    float wv[8] = {w0.x, w0.y, w0.z, w0.w, w1.x, w1.y, w1.z, w1.w};
                    #pragma unroll
                    for (int j2 = 0; j2 < 8; ++j2)
                        f[q*8 + j2] = fmaf(b2f((ushortT)v[j2]), wv[j2], f[q*8 + j2]);
                }
            }
        }
        float s1 = 0.f, s2 = 0.f;
        #pragma unroll
        for (int j = 0; j < 16; ++j) { s1 += f[j]; s2 += f[j] * f[j]; }
        #pragma unroll
        for (int off = 8; off; off >>= 1) {
            s1 += __shfl_xor(s1, off);
            s2 += __shfl_xor(s2, off);
        }
        float mean = s1 * (1.0f / CC);
        float var  = s2 * (1.0f / CC) - mean * mean;
        float rs = rsqrtf(var + EPSV);
        #pragma unroll
        for (int q = 0; q < 2; ++q) {
            float4 g0 = *(const float4*)(ln_g + c0 + q * 8);
            float4 g1 = *(const float4*)(ln_g + c0 + q * 8 + 4);
            float4 e0 = *(const float4*)(ln_b + c0 + q * 8);
            float4 e1 = *(const float4*)(ln_b + c0 + q * 8 + 4);
            float gv[8] = {g0.x, g0.y, g0.z, g0.w, g1.x, g1.y, g1.z, g1.w};
            float ev[8] = {e0.x, e0.y, e0.z, e0.w, e1.x, e1.y, e1.z, e1.w};
            short8 sv;
            #pragma unroll
            for (int j2 = 0; j2 < 8; ++j2) {
                float v = (f[q*8 + j2] - mean) * rs * gv[j2] + ev[j2];
                float u2 = 1.5957691216057308f * (v + 0.044715f * v * v * v);
                v = v * __frcp_rn(1.0f + __expf(-u2));
                sv[j2] = (short)f2b(v);
            }
            *(short8*)(&sfeat[pxl * 264 + c0 + q * 8]) = sv;
        }
    }
    __syncthreads();

    if (w < 4) {
        int mt = w >> 1, nt = w & 1;
        floatx4 acc = {0.f, 0.f, 0.f, 0.f};
        #pragma unroll
        for (int kt = 0; kt < 8; ++kt) {
            short8 af  = *(const short8*)(&sfeat[(mt * 16 + cl) * 264 + kt * 32 + rg * 8]);
            short8 bf2 = *(const short8*)(Whf + ((size_t)((nt * 8 + kt) * 64 + lane)) * 8);
            acc = __builtin_amdgcn_mfma_f32_16x16x32_bf16(af, bf2, acc, 0, 0, 0);
        }
        int col = nt * 16 + cl;
        float bias = (col < 18) ? off_b[col] : ((col < 27) ? mask_b[col - 18] : 0.f);
        #pragma unroll
        for (int j = 0; j < 4; ++j) {
            int row = mt * 16 + rg * 4 + j;
            O[row * 36 + col] = acc[j] + bias;
        }
    }
    __syncthreads();

    if (t < 32) {
        float* row = O + t * 36 + 18;
        float mx = row[0];
        #pragma unroll
        for (int k = 1; k < 9; ++k) mx = fmaxf(mx, row[k]);
        float e9[9], ssum = 0.f;
        #pragma unroll
        for (int k = 0; k < 9; ++k) { e9[k] = __expf(row[k] - mx); ssum += e9[k]; }
        float inv = __frcp_rn(ssum);
        #pragma unroll
        for (int k = 0; k < 9; ++k) row[k] = e9[k] * inv;
    }
    __syncthreads();
    #pragma unroll
    for (int i = 0; i < 2; ++i) {
        int idx = t + i * 512;
        int p = idx >> 5, jj = idx & 31;
        offmask[((size_t)blk * 32 + p) * 32 + jj] = O[p * 36 + jj];
    }
}

// ---------------- KG: deformable gather -> accg bf16 + per-pixel weight sums ----------------
// round-4 k4 shape (proven): 4096 blocks XCD-chunked, 256 threads, 8 px/block,
// LDS-staged idx/w, one short8 octet per thread, uniform 36-corner loop.
__global__ __launch_bounds__(256) void kG(const ushortT* __restrict__ x1t,
        const float* __restrict__ offmask, ushortT* __restrict__ accg,
        float* __restrict__ sums) {
    int blk = ((blockIdx.x & 7) << 9) | (blockIdx.x >> 3);   // XCD-chunked bijection (4096)
    int p0 = blk * 8;
    int t = threadIdx.x;
    __shared__ int   s_idx[8][9][4];
    __shared__ float s_w[8][9][4];
    if (t < 72) {
        int pxi = t / 9, k = t - pxi * 9;
        int p = p0 + pxi;
        int x = p & 63, y = (p >> 6) & 63, b = p >> 12;
        float dxo = offmask[(size_t)p * 32 + 2 * k];
        float dyo = offmask[(size_t)p * 32 + 2 * k + 1];
        float mk  = offmask[(size_t)p * 32 + 18 + k];
        float py  = (float)y + (float)(k / 3 - 1) + dyo;
        float pxf = (float)x + (float)(k % 3 - 1) + dxo;
        float y0f = floorf(py), x0f = floorf(pxf);
        float wy = py - y0f, wx = pxf - x0f;
        int y0 = (int)y0f, x0 = (int)x0f;
        int y1 = y0 + 1, x1i = x0 + 1;
        float vy0 = (y0 >= 0 && y0 < HH) ? 1.f : 0.f;
        float vy1 = (y1 >= 0 && y1 < HH) ? 1.f : 0.f;
        float vx0 = (x0 >= 0 && x0 < WW) ? 1.f : 0.f;
        float vx1 = (x1i >= 0 && x1i < WW) ? 1.f : 0.f;
        int yc0 = max(0, min(HH - 1, y0)), yc1 = max(0, min(HH - 1, y1));
        int xc0 = max(0, min(WW - 1, x0)), xc1 = max(0, min(WW - 1, x1i));
        int base = b * HH * WW;
        s_idx[pxi][k][0] = (base + yc0 * WW + xc0) * CC;
        s_idx[pxi][k][1] = (base + yc0 * WW + xc1) * CC;
        s_idx[pxi][k][2] = (base + yc1 * WW + xc0) * CC;
        s_idx[pxi][k][3] = (base + yc1 * WW + xc1) * CC;
        s_w[pxi][k][0] = mk * (1.f - wy) * (1.f - wx) * vy0 * vx0;
        s_w[pxi][k][1] = mk * (1.f - wy) * wx * vy0 * vx1;
        s_w[pxi][k][2] = mk * wy * (1.f - wx) * vy1 * vx0;
        s_w[pxi][k][3] = mk * wy * wx * vy1 * vx1;
    }
    __syncthreads();
    if (t < 8) {
        float s = 0.f;
        const float* wq = &s_w[t][0][0];
        #pragma unroll
        for (int q = 0; q < 36; ++q) s += wq[q];
        sums[p0 + t] = s;
    }
    int px = t >> 5, cg = t & 31, c0 = cg * 8;
    const float* wp = &s_w[px][0][0];
    const int*   ip = &s_idx[px][0][0];
    float f[8] = {};
    #pragma unroll
    for (int q = 0; q < 36; ++q) {
        float wv = wp[q];
        short8 v = *(const short8*)(x1t + ip[q] + c0);
        #pragma unroll
        for (int j = 0; j < 8; ++j)
            f[j] = fmaf(wv, b2f((ushortT)v[j]), f[j]);
    }
    short8 sv;
    #pragma unroll
    for (int j = 0; j < 8; ++j) sv[j] = (short)f2b(f[j]);
    *(short8*)(accg + (size_t)(p0 + px) * CC + c0) = sv;
}

// ---------------- KGEMM: out = accg @ W_comb + sums*bwout + BN + ReLU + residual ----------
// Pure GEMM (no gather): BM=32, 1024 blocks XCD-chunked, 256 threads = 4 waves.
__global__ __launch_bounds__(256, 4) void kGEMM(const ushortT* __restrict__ accg,
        const float* __restrict__ sums, const ushortT* __restrict__ Bf,
        const float* __restrict__ bwout, const float* __restrict__ out_b,
        const float* __restrict__ bn_g, const float* __restrict__ bn_b,
        const float* __restrict__ bn_mean, const float* __restrict__ bn_var,
        const float* __restrict__ x1, float* __restrict__ out) {
    __shared__ __align__(16) char smem[20224];
    short* Asb     = (short*)smem;                   // [32][264] 16896 B
    float* s_scale = (float*)(smem + 16896);         // [256] 1024 B
    float* s_shift = (float*)(smem + 17920);         // [256] 1024 B
    float* s_bw    = (float*)(smem + 18944);         // [256] 1024 B
    float* s_sumL  = (float*)(smem + 19968);         // [32]   128 B
    float* Lo      = (float*)smem;                   // epi reuse: [32][129] f32 = 16512 B

    int t = threadIdx.x;
    int blk = ((blockIdx.x & 7) << 7) | (blockIdx.x >> 3);  // XCD-chunked bijection (1024)
    int m0 = blk * 32;
    int b = m0 >> 12, y = (m0 >> 6) & 63, xb = m0 & 63;
    int lane = t & 63, w = t >> 6;
    int cl = lane & 15, rg = lane >> 4;

    {
        float scale = bn_g[t] * rsqrtf(bn_var[t] + EPSV);
        s_scale[t] = scale;
        s_shift[t] = out_b[t] * scale + bn_b[t] - bn_mean[t] * scale;
        s_bw[t]    = bwout[t] * scale;
    }
    if (t < 32) s_sumL[t] = sums[m0 + t];
    // one-shot A stage: 32 px x 256 ch bf16, coalesced short8
    #pragma unroll
    for (int i = 0; i < 4; ++i) {
        int e = t + i * 256;                 // 0..1023
        int px = e >> 5, oct = e & 31;
        *(short8*)(&Asb[px * 264 + oct * 8]) =
            *(const short8*)(accg + (size_t)(m0 + px) * CC + oct * 8);
    }
    __syncthreads();

    floatx4 acc[2][4];
    floatx4 zero = {0.f, 0.f, 0.f, 0.f};
    #pragma unroll
    for (int i = 0; i < 2; ++i)
        #pragma unroll
        for (int j = 0; j < 4; ++j) acc[i][j] = zero;

    #pragma unroll
    for (int kt = 0; kt < 8; ++kt) {
        short8 af[2], bfr[4];
        #pragma unroll
        for (int f = 0; f < 2; ++f)
            af[f] = *(const short8*)(&Asb[(f * 16 + cl) * 264 + kt * 32 + rg * 8]);
        #pragma unroll
        for (int fc = 0; fc < 4; ++fc)
            bfr[fc] = *(const short8*)(Bf + ((size_t)((w * 4 + fc) * 8 + kt) * 64 + lane) * 8);
        #pragma unroll
        for (int fr = 0; fr < 2; ++fr)
            #pragma unroll
            for (int fc = 0; fc < 4; ++fc)
                acc[fr][fc] = __builtin_amdgcn_mfma_f32_16x16x32_bf16(
                    af[fr], bfr[fc], acc[fr][fc], 0, 0, 0);
    }
    __syncthreads();   // all waves done reading Asb before Lo overwrite

    // epilogue: 2 phases of 128 channels; Lo bounce -> BN+ReLU+residual NCHW stores
    #pragma unroll
    for (int ph = 0; ph < 2; ++ph) {
        if ((w >> 1) == ph) {
            #pragma unroll
            for (int fc = 0; fc < 4; ++fc) {
                int cloc = (w & 1) * 64 + fc * 16 + cl;
                #pragma unroll
                for (int fr = 0; fr < 2; ++fr) {
                    int mr = fr * 16 + rg * 4;
                    #pragma unroll
                    for (int j = 0; j < 4; ++j)
                        Lo[(mr + j) * 129 + cloc] = acc[fr][fc][j];
                }
            }
        }
        __syncthreads();
        #pragma unroll
        for (int i = 0; i < 16; ++i) {
            int e = t + i * 256;              // 0..4095 = 32 px x 128 ch
            int xl = e & 31, cw = e >> 5;
            int co = ph * 128 + cw;
            float val = Lo[xl * 129 + cw] * s_scale[co] + s_sumL[xl] * s_bw[co] + s_shift[co];
            val = fmaxf(val, 0.f);
            size_t g = (size_t)((b * CC + co) * HH + y) * WW + xb + xl;
            out[g] = val + x1[g];
        }
        __syncthreads();
    }
}

extern "C" void kernel_launch(void* const* d_in, const int* in_sizes, int n_in,
                              void* d_out, int out_size, void* d_ws, size_t ws_size,
                              hipStream_t stream) {
    const float* x1     = (const float*)d_in[0];
    const float* x2     = (const float*)d_in[1];
    const float* dw_w   = (const float*)d_in[2];
    const float* dw_b   = (const float*)d_in[3];
    const float* ln_g   = (const float*)d_in[4];
    const float* ln_b   = (const float*)d_in[5];
    const float* off_w  = (const float*)d_in[6];
    const float* off_b  = (const float*)d_in[7];
    const float* mask_w = (const float*)d_in[8];
    const float* mask_b = (const float*)d_in[9];
    const float* in_w   = (const float*)d_in[10];
    const float* in_b   = (const float*)d_in[11];
    const float* out_w  = (const float*)d_in[12];
    const float* out_b  = (const float*)d_in[13];
    const float* bn_g   = (const float*)d_in[14];
    const float* bn_b   = (const float*)d_in[15];
    const float* bn_mean= (const float*)d_in[16];
    const float* bn_var = (const float*)d_in[17];
    float* out = (float*)d_out;

    char* wsb = (char*)d_ws;
    const size_t SZ = (size_t)NPIX * CC * 2;        // 16.78 MB per bf16 tensor
    ushortT* guide   = (ushortT*)wsb;               // slot0 (k1_both out, k2ab in)
    ushortT* x1t     = (ushortT*)(wsb + SZ);        // slot1 (k1_both out, kG in)
    float*   offmask = (float*)(wsb + 2 * SZ);      // 4.19 MB
    float*   bwout   = offmask + (size_t)NPIX * 32; // 1 KB
    ushortT* Bf      = (ushortT*)(bwout + CC);      // 128 KB bf16
    ushortT* Whf     = Bf + (size_t)CC * CC;        // 16 KB bf16
    float*   sums    = (float*)(Whf + 8192);        // 128 KB f32
    ushortT* accg    = guide;                       // guide dead after k2ab -> alias

    hipLaunchKernelGGL(k1_both, dim3(4357), dim3(256), 0, stream, x2, x1, in_w, in_b,
                       out_w, off_w, mask_w, guide, x1t, Bf, bwout, Whf);
    hipLaunchKernelGGL(k2ab,    dim3(1024), dim3(512), 0, stream, guide, dw_w, dw_b,
                       ln_g, ln_b, Whf, off_b, mask_b, offmask);
    hipLaunchKernelGGL(kG,      dim3(4096), dim3(256), 0, stream, x1t, offmask, accg, sums);
    hipLaunchKernelGGL(kGEMM,   dim3(1024), dim3(256), 0, stream, accg, sums, Bf,
                       bwout, out_b, bn_g, bn_b, bn_mean, bn_var, x1, out);
}

// Round 21
// 95.726 us; speedup vs baseline: 1.0612x; 1.0612x over previous
//
#include <hip/hip_runtime.h>
#include <math.h>

#define BB 8
#define CC 256
#define HH 64
#define WW 64
#define H2 32
#define W2 32
#define NPIX (BB*HH*WW)
#define EPSV 1e-5f

typedef unsigned short ushortT;
using short8  = __attribute__((ext_vector_type(8))) short;
using floatx4 = __attribute__((ext_vector_type(4))) float;

__device__ inline float b2f(ushortT u) {
    unsigned int x = ((unsigned int)u) << 16;
    float f; __builtin_memcpy(&f, &x, 4); return f;
}
__device__ inline ushortT f2b(float f) {
    unsigned int x; __builtin_memcpy(&x, &f, 4);
    unsigned int r = x + 0x7fffu + ((x >> 16) & 1u);   // RNE
    return (ushortT)(r >> 16);
}

// ---------------- K1both v4: low-LDS (21.2KB -> 7 blocks/CU) ----------------
// blk <  4096          : guide, 32-ch granularity (b, y, c0=32*(blk&7))
// 4096 <= blk < 6144   : x1t transpose (64-ch tiles, as r18)
// 6144 <= blk < 6401   : W_comb row -> Bf fragment scatter (j = blk-6144; j==256 -> bwout)
// 6401 <= blk < 6405   : Whf head-weight fragments
__global__ __launch_bounds__(256) void k1_both(const float* __restrict__ x2,
        const float* __restrict__ x1, const float* __restrict__ in_w,
        const float* __restrict__ in_b, const float* __restrict__ out_w,
        const float* __restrict__ off_w, const float* __restrict__ mask_w,
        ushortT* __restrict__ guide, ushortT* __restrict__ x1t,
        ushortT* __restrict__ Bf, float* __restrict__ bwout,
        ushortT* __restrict__ Whf) {
    __shared__ __align__(16) char smem[21248];
    int blk0 = blockIdx.x;
    int t = threadIdx.x;

    if (blk0 >= 6401) {
        int s = (blk0 - 6401) * 256 + t;                  // 0..1023
        int lane = s & 63;
        int kt = (s >> 6) & 7;
        int nt = s >> 9;
        int n = nt * 16 + (lane & 15);
        int k = kt * 32 + (lane >> 4) * 8;
        short8 o;
        #pragma unroll
        for (int j = 0; j < 8; ++j) {
            float wv = 0.f;
            int kk = k + j;
            if (n < 18)      wv = off_w[kk * 18 + n];
            else if (n < 27) wv = mask_w[kk * 9 + (n - 18)];
            o[j] = (short)f2b(wv);
        }
        *(short8*)(Whf + (size_t)s * 8) = o;
        return;
    }
    if (blk0 >= 6144) {
        float* Wl = (float*)smem;                         // 256 floats
        int j = blk0 - 6144;
        int n = t;
        Wl[n] = (j < CC) ? in_w[(size_t)j * CC + n] : in_b[n];
        __syncthreads();
        float acc = 0.f;
        #pragma unroll 8
        for (int k = 0; k < CC; ++k)
            acc = fmaf(Wl[k], out_w[(size_t)k * CC + n], acc);
        if (j < CC) {
            int lane = (((j >> 3) & 3) << 4) | (n & 15);
            size_t idx = ((size_t)(((n >> 4) * 8 + (j >> 5)) * 64 + lane)) * 8 + (j & 7);
            Bf[idx] = f2b(acc);
        } else {
            bwout[n] = acc;
        }
        return;
    }

    if (blk0 < 4096) {
        // guide: 32 channels per block
        float*   Xs   = (float*)smem;                     // [64][2][33] f32 = 16896 B
        ushortT* tile = (ushortT*)(smem + 16896);         // [64][34] = 4352 B
        int c0 = (blk0 & 7) * 32;
        int y  = (blk0 >> 3) & 63;
        int b  = blk0 >> 9;
        int bb = b & 3;
        float sy = 0.5f * y - 0.25f;
        float fy0 = floorf(sy);
        float wy = sy - fy0;
        int jy0 = (int)fy0;
        int iy0 = max(0, min(H2 - 1, jy0));
        int iy1 = max(0, min(H2 - 1, jy0 + 1));
        // stage 2 tensors x 32 ch x 2 rows: 1024 float4, coalesced
        #pragma unroll
        for (int i = 0; i < 4; ++i) {
            int e = t + i * 256;
            int q = e >> 9, ch = (e >> 4) & 31, r = (e >> 3) & 1, xg = (e & 7) * 4;
            int iy = r ? iy1 : iy0;
            float4 v = *(const float4*)(x2 +
                (size_t)(((bb + 4 * q) * CC + c0 + ch) * H2 + iy) * W2 + xg);
            float* dst = Xs + (size_t)((q * 32 + ch) * 2 + r) * 33 + xg;
            dst[0] = v.x; dst[1] = v.y; dst[2] = v.z; dst[3] = v.w;
        }
        __syncthreads();
        int x = t & 63, cl = t >> 6;
        float sx = 0.5f * x - 0.25f;
        float fx0 = floorf(sx);
        float wx = sx - fx0;
        int jx0 = (int)fx0;
        int ix0 = max(0, min(W2 - 1, jx0));
        int ix1 = max(0, min(W2 - 1, jx0 + 1));
        float w00 = (1.f - wy) * (1.f - wx), w01 = (1.f - wy) * wx;
        float w10 = wy * (1.f - wx), w11 = wy * wx;
        #pragma unroll
        for (int it = 0; it < 8; ++it) {
            int c = cl + it * 4;                          // 0..31
            const float* a  = Xs + (size_t)(c * 2) * 33;
            const float* bq = Xs + (size_t)((32 + c) * 2) * 33;
            float v1 = w00 * a[ix0]  + w01 * a[ix1]  + w10 * a[33 + ix0]  + w11 * a[33 + ix1];
            float v2 = w00 * bq[ix0] + w01 * bq[ix1] + w10 * bq[33 + ix0] + w11 * bq[33 + ix1];
            tile[x * 34 + c] = f2b(fabsf(v1 - v2));
        }
        __syncthreads();
        {
            int px = t >> 2, oct = t & 3;                 // 64 px x 4 octets (32 ch)
            uint4 o;
            o.x = *(const unsigned int*)(&tile[px * 34 + oct * 8 + 0]);
            o.y = *(const unsigned int*)(&tile[px * 34 + oct * 8 + 2]);
            o.z = *(const unsigned int*)(&tile[px * 34 + oct * 8 + 4]);
            o.w = *(const unsigned int*)(&tile[px * 34 + oct * 8 + 6]);
            *(uint4*)(guide + (size_t)((b * HH + y) * WW + px) * CC + c0 + oct * 8) = o;
        }
    } else {
        // x1t transpose: 64-ch tiles
        ushortT* tile = (ushortT*)smem;                   // [64][66] = 8448 B
        int blk = blk0 - 4096;
        int c0 = (blk & 3) * 64;
        int y  = (blk >> 2) & 63;
        int b  = blk >> 8;
        #pragma unroll
        for (int i = 0; i < 4; ++i) {
            int e = t + i * 256;
            int ch = e >> 4, xq = (e & 15) * 4;
            float4 v = *(const float4*)(x1 + (size_t)((b * CC + c0 + ch) * HH + y) * WW + xq);
            tile[(xq + 0) * 66 + ch] = f2b(v.x);
            tile[(xq + 1) * 66 + ch] = f2b(v.y);
            tile[(xq + 2) * 66 + ch] = f2b(v.z);
            tile[(xq + 3) * 66 + ch] = f2b(v.w);
        }
        __syncthreads();
        #pragma unroll
        for (int i = 0; i < 2; ++i) {
            int e = t + i * 256;
            int px = e >> 3, oct = e & 7;
            uint4 o;
            o.x = *(const unsigned int*)(&tile[px * 66 + oct * 8 + 0]);
            o.y = *(const unsigned int*)(&tile[px * 66 + oct * 8 + 2]);
            o.z = *(const unsigned int*)(&tile[px * 66 + oct * 8 + 4]);
            o.w = *(const unsigned int*)(&tile[px * 66 + oct * 8 + 6]);
            *(uint4*)(x1t + (size_t)((b * HH + y) * WW + px) * CC + c0 + oct * 8) = o;
        }
    }
}

// ---------------- K2ab: dwconv3x3 + LN + GELU (LDS feat) + MFMA heads + softmax -------- r14
__global__ __launch_bounds__(512, 4) void k2ab(const ushortT* __restrict__ guide,
        const float* __restrict__ dw_w, const float* __restrict__ dw_b,
        const float* __restrict__ ln_g, const float* __restrict__ ln_b,
        const ushortT* __restrict__ Whf, const float* __restrict__ off_b,
        const float* __restrict__ mask_b, float* __restrict__ offmask) {
    __shared__ __align__(16) short sfeat[32 * 264];
    __shared__ float O[32 * 36];
    int t = threadIdx.x;
    int blk = ((blockIdx.x & 7) << 7) | (blockIdx.x >> 3);
    int b = blk >> 7, y = (blk >> 1) & 63, xh = (blk & 1) * 32;
    int lane = t & 63, w = t >> 6;
    int cl = lane & 15, rg = lane >> 4;

    {
        int pxl = t >> 4, s = t & 15;
        int c0 = s * 16;
        int xg = xh + pxl;
        float f[16];
        #pragma unroll
        for (int q = 0; q < 4; ++q) {
            float4 d = *(const float4*)(dw_b + c0 + q * 4);
            f[q*4+0]=d.x; f[q*4+1]=d.y; f[q*4+2]=d.z; f[q*4+3]=d.w;
        }
        #pragma unroll
        for (int tap = 0; tap < 9; ++tap) {
            int dy = tap / 3 - 1, dxx = tap % 3 - 1;
            int yy = y + dy, xx = xg + dxx;
            if (yy >= 0 && yy < HH && xx >= 0 && xx < WW) {
                const ushortT* gp = guide + (size_t)((b * HH + yy) * WW + xx) * CC + c0;
                #pragma unroll
                for (int q = 0; q < 2; ++q) {
                    short8 v = *(const short8*)(gp + q * 8);
                    float4 w0 = *(const float4*)(dw_w + tap * CC + c0 + q * 8);
                    float4 w1 = *(const float4*)(dw_w + tap * CC + c0 + q * 8 + 4);
                    float wv[8] = {w0.x, w0.y, w0.z, w0.w, w1.x, w1.y, w1.z, w1.w};
                    #pragma unroll
                    for (int j2 = 0; j2 < 8; ++j2)
                        f[q*8 + j2] = fmaf(b2f((ushortT)v[j2]), wv[j2], f[q*8 + j2]);
                }
            }
        }
        float s1 = 0.f, s2 = 0.f;
        #pragma unroll
        for (int j = 0; j < 16; ++j) { s1 += f[j]; s2 += f[j] * f[j]; }
        #pragma unroll
        for (int off = 8; off; off >>= 1) {
            s1 += __shfl_xor(s1, off);
            s2 += __shfl_xor(s2, off);
        }
        float mean = s1 * (1.0f / CC);
        float var  = s2 * (1.0f / CC) - mean * mean;
        float rs = rsqrtf(var + EPSV);
        #pragma unroll
        for (int q = 0; q < 2; ++q) {
            float4 g0 = *(const float4*)(ln_g + c0 + q * 8);
            float4 g1 = *(const float4*)(ln_g + c0 + q * 8 + 4);
            float4 e0 = *(const float4*)(ln_b + c0 + q * 8);
            float4 e1 = *(const float4*)(ln_b + c0 + q * 8 + 4);
            float gv[8] = {g0.x, g0.y, g0.z, g0.w, g1.x, g1.y, g1.z, g1.w};
            float ev[8] = {e0.x, e0.y, e0.z, e0.w, e1.x, e1.y, e1.z, e1.w};
            short8 sv;
            #pragma unroll
            for (int j2 = 0; j2 < 8; ++j2) {
                float v = (f[q*8 + j2] - mean) * rs * gv[j2] + ev[j2];
                float u2 = 1.5957691216057308f * (v + 0.044715f * v * v * v);
                v = v * __frcp_rn(1.0f + __expf(-u2));
                sv[j2] = (short)f2b(v);
            }
            *(short8*)(&sfeat[pxl * 264 + c0 + q * 8]) = sv;
        }
    }
    __syncthreads();

    if (w < 4) {
        int mt = w >> 1, nt = w & 1;
        floatx4 acc = {0.f, 0.f, 0.f, 0.f};
        #pragma unroll
        for (int kt = 0; kt < 8; ++kt) {
            short8 af  = *(const short8*)(&sfeat[(mt * 16 + cl) * 264 + kt * 32 + rg * 8]);
            short8 bf2 = *(const short8*)(Whf + ((size_t)((nt * 8 + kt) * 64 + lane)) * 8);
            acc = __builtin_amdgcn_mfma_f32_16x16x32_bf16(af, bf2, acc, 0, 0, 0);
        }
        int col = nt * 16 + cl;
        float bias = (col < 18) ? off_b[col] : ((col < 27) ? mask_b[col - 18] : 0.f);
        #pragma unroll
        for (int j = 0; j < 4; ++j) {
            int row = mt * 16 + rg * 4 + j;
            O[row * 36 + col] = acc[j] + bias;
        }
    }
    __syncthreads();

    if (t < 32) {
        float* row = O + t * 36 + 18;
        float mx = row[0];
        #pragma unroll
        for (int k = 1; k < 9; ++k) mx = fmaxf(mx, row[k]);
        float e9[9], ssum = 0.f;
        #pragma unroll
        for (int k = 0; k < 9; ++k) { e9[k] = __expf(row[k] - mx); ssum += e9[k]; }
        float inv = __frcp_rn(ssum);
        #pragma unroll
        for (int k = 0; k < 9; ++k) row[k] = e9[k] * inv;
    }
    __syncthreads();
    #pragma unroll
    for (int i = 0; i < 2; ++i) {
        int idx = t + i * 512;
        int p = idx >> 5, jj = idx & 31;
        offmask[((size_t)blk * 32 + p) * 32 + jj] = O[p * 36 + jj];
    }
}

// ---------------- K45: fused gather + combined-proj GEMM (r19 version, 41.7us/27MB) --------
#define GATHER_CHUNK(K0) do {                                            \
        int c_ = (K0) + o8 * 8;                                          \
        _Pragma("unroll")                                                \
        for (int q = 0; q < 36; ++q) {                                   \
            float wv_ = wp[q];                                           \
            short8 v_ = *(const short8*)(x1t + ip[q] + c_);              \
            _Pragma("unroll")                                            \
            for (int j = 0; j < 8; ++j)                                  \
                f[j] = fmaf(wv_, b2f((ushortT)v_[j]), f[j]);             \
        }                                                                \
    } while (0)

__global__ __launch_bounds__(512, 4) void k45_fused(const ushortT* __restrict__ x1t,
        const float* __restrict__ offmask, const ushortT* __restrict__ Bf,
        const float* __restrict__ bwout, const float* __restrict__ out_b,
        const float* __restrict__ bn_g, const float* __restrict__ bn_b,
        const float* __restrict__ bn_mean, const float* __restrict__ bn_var,
        const float* __restrict__ x1, float* __restrict__ out) {
    __shared__ __align__(16) char smem[40192];
    short* Asb     = (short*)smem;                   // [2][64][72] 18432 B
    float* s_w     = (float*)(smem + 18432);         // [64][9][4]   9216 B
    int*   s_idx   = (int*)(smem + 27648);           // [64][9][4]   9216 B
    float* s_scale = (float*)(smem + 36864);         // [256] 1024 B
    float* s_shift = (float*)(smem + 37888);         // [256] 1024 B
    float* s_bw    = (float*)(smem + 38912);         // [256] 1024 B
    float* s_sum   = (float*)(smem + 39936);         // [64]   256 B
    float* Lo      = (float*)smem;                   // epilogue reuse: [64][65] f32

    int t = threadIdx.x;
    int bm = ((blockIdx.x & 7) << 6) | (blockIdx.x >> 3);   // XCD-chunked bijection (512)
    int m0 = bm * 64;
    int b = bm >> 6, y = bm & 63;
    int lane = t & 63, w = t >> 6;
    int cl = lane & 15, rg = lane >> 4;

    if (t < 256) {
        float scale = bn_g[t] * rsqrtf(bn_var[t] + EPSV);
        s_scale[t] = scale;
        s_shift[t] = out_b[t] * scale + bn_b[t] - bn_mean[t] * scale;
        s_bw[t]    = bwout[t] * scale;
    }
    for (int e = t; e < 576; e += 512) {
        int px = e / 9, k = e - px * 9;
        int p = m0 + px;
        float dxo = offmask[(size_t)p * 32 + 2 * k];
        float dyo = offmask[(size_t)p * 32 + 2 * k + 1];
        float mk  = offmask[(size_t)p * 32 + 18 + k];
        float py  = (float)y  + (float)(k / 3 - 1) + dyo;
        float pxf = (float)px + (float)(k % 3 - 1) + dxo;
        float y0f = floorf(py), x0f = floorf(pxf);
        float wy = py - y0f, wx = pxf - x0f;
        int y0 = (int)y0f, x0 = (int)x0f;
        int y1 = y0 + 1, x1i = x0 + 1;
        float vy0 = (y0 >= 0 && y0 < HH) ? 1.f : 0.f;
        float vy1 = (y1 >= 0 && y1 < HH) ? 1.f : 0.f;
        float vx0 = (x0 >= 0 && x0 < WW) ? 1.f : 0.f;
        float vx1 = (x1i >= 0 && x1i < WW) ? 1.f : 0.f;
        int yc0 = max(0, min(HH - 1, y0)), yc1 = max(0, min(HH - 1, y1));
        int xc0 = max(0, min(WW - 1, x0)), xc1 = max(0, min(WW - 1, x1i));
        int base = b * HH * WW;
        int o = (px * 9 + k) * 4;
        s_idx[o + 0] = (base + yc0 * WW + xc0) * CC;
        s_idx[o + 1] = (base + yc0 * WW + xc1) * CC;
        s_idx[o + 2] = (base + yc1 * WW + xc0) * CC;
        s_idx[o + 3] = (base + yc1 * WW + xc1) * CC;
        s_w[o + 0] = mk * (1.f - wy) * (1.f - wx) * vy0 * vx0;
        s_w[o + 1] = mk * (1.f - wy) * wx * vy0 * vx1;
        s_w[o + 2] = mk * wy * (1.f - wx) * vy1 * vx0;
        s_w[o + 3] = mk * wy * wx * vy1 * vx1;
    }
    __syncthreads();
    if (t < 64) {
        float s = 0.f;
        #pragma unroll
        for (int q = 0; q < 36; ++q) s += s_w[t * 36 + q];
        s_sum[t] = s;
    }
    __syncthreads();

    int px = t >> 3, o8 = t & 7;
    const float* wp = s_w  + px * 36;
    const int*   ip = s_idx + px * 36;

    floatx4 acc[4][2];
    floatx4 zero = {0.f, 0.f, 0.f, 0.f};
    #pragma unroll
    for (int i = 0; i < 4; ++i)
        #pragma unroll
        for (int j = 0; j < 2; ++j) acc[i][j] = zero;

    {
        float f[8] = {};
        GATHER_CHUNK(0);
        short8 sv;
        #pragma unroll
        for (int j = 0; j < 8; ++j) sv[j] = (short)f2b(f[j]);
        *(short8*)(&Asb[px * 72 + o8 * 8]) = sv;
    }
    __syncthreads();

    #pragma unroll
    for (int kc = 0; kc < 4; ++kc) {
        int cur = kc & 1;
        float f[8] = {};
        if (kc < 3)
            GATHER_CHUNK((kc + 1) * 64);
        {
            const short* Ab = Asb + cur * 4608;
            int kt0 = kc * 2;
            #pragma unroll
            for (int kk = 0; kk < 2; ++kk) {
                short8 af[4], bfr[2];
                #pragma unroll
                for (int fr2 = 0; fr2 < 4; ++fr2)
                    af[fr2] = *(const short8*)(&Ab[(fr2 * 16 + cl) * 72 + kk * 32 + rg * 8]);
                #pragma unroll
                for (int fc = 0; fc < 2; ++fc)
                    bfr[fc] = *(const short8*)(Bf + ((size_t)((w * 2 + fc) * 8 + kt0 + kk) * 64 + lane) * 8);
                #pragma unroll
                for (int fr2 = 0; fr2 < 4; ++fr2)
                    #pragma unroll
                    for (int fc = 0; fc < 2; ++fc)
                        acc[fr2][fc] = __builtin_amdgcn_mfma_f32_16x16x32_bf16(
                            af[fr2], bfr[fc], acc[fr2][fc], 0, 0, 0);
            }
        }
        if (kc < 3) {
            short8 sv;
            #pragma unroll
            for (int j = 0; j < 8; ++j) sv[j] = (short)f2b(f[j]);
            *(short8*)(&Asb[(cur ^ 1) * 4608 + px * 72 + o8 * 8]) = sv;
        }
        __syncthreads();
    }

    #pragma unroll
    for (int ph = 0; ph < 4; ++ph) {
        if ((w >> 1) == ph) {
            #pragma unroll
            for (int fc = 0; fc < 2; ++fc) {
                int cloc = (w & 1) * 32 + fc * 16 + cl;
                #pragma unroll
                for (int fr2 = 0; fr2 < 4; ++fr2) {
                    int mr = fr2 * 16 + rg * 4;
                    #pragma unroll
                    for (int j = 0; j < 4; ++j)
                        Lo[(mr + j) * 65 + cloc] = acc[fr2][fc][j];
                }
            }
        }
        __syncthreads();
        #pragma unroll
        for (int i = 0; i < 8; ++i) {
            int e = t + i * 512;
            int xl = e & 63, cw = e >> 6;
            int co = ph * 64 + cw;
            float val = Lo[xl * 65 + cw] * s_scale[co] + s_sum[xl] * s_bw[co] + s_shift[co];
            val = fmaxf(val, 0.f);
            size_t g = (size_t)((b * CC + co) * HH + y) * WW + xl;
            out[g] = val + x1[g];
        }
        __syncthreads();
    }
}

extern "C" void kernel_launch(void* const* d_in, const int* in_sizes, int n_in,
                              void* d_out, int out_size, void* d_ws, size_t ws_size,
                              hipStream_t stream) {
    const float* x1     = (const float*)d_in[0];
    const float* x2     = (const float*)d_in[1];
    const float* dw_w   = (const float*)d_in[2];
    const float* dw_b   = (const float*)d_in[3];
    const float* ln_g   = (const float*)d_in[4];
    const float* ln_b   = (const float*)d_in[5];
    const float* off_w  = (const float*)d_in[6];
    const float* off_b  = (const float*)d_in[7];
    const float* mask_w = (const float*)d_in[8];
    const float* mask_b = (const float*)d_in[9];
    const float* in_w   = (const float*)d_in[10];
    const float* in_b   = (const float*)d_in[11];
    const float* out_w  = (const float*)d_in[12];
    const float* out_b  = (const float*)d_in[13];
    const float* bn_g   = (const float*)d_in[14];
    const float* bn_b   = (const float*)d_in[15];
    const float* bn_mean= (const float*)d_in[16];
    const float* bn_var = (const float*)d_in[17];
    float* out = (float*)d_out;

    char* wsb = (char*)d_ws;
    const size_t SZ = (size_t)NPIX * CC * 2;        // 16.78 MB per bf16 tensor
    ushortT* guide   = (ushortT*)wsb;               // slot0 (k1_both out, k2ab in)
    ushortT* x1t     = (ushortT*)(wsb + SZ);        // slot1 (k1_both out, k45 in)
    float*   offmask = (float*)(wsb + 2 * SZ);      // 4.19 MB
    float*   bwout   = offmask + (size_t)NPIX * 32; // 1 KB
    ushortT* Bf      = (ushortT*)(bwout + CC);      // 128 KB bf16 (16B-aligned)
    ushortT* Whf     = Bf + (size_t)CC * CC;        // 16 KB bf16

    hipLaunchKernelGGL(k1_both, dim3(6405), dim3(256), 0, stream, x2, x1, in_w, in_b,
                       out_w, off_w, mask_w, guide, x1t, Bf, bwout, Whf);
    hipLaunchKernelGGL(k2ab,    dim3(1024), dim3(512), 0, stream, guide, dw_w, dw_b,
                       ln_g, ln_b, Whf, off_b, mask_b, offmask);
    hipLaunchKernelGGL(k45_fused, dim3(512), dim3(512), 0, stream, x1t, offmask, Bf,
                       bwout, out_b, bn_g, bn_b, bn_mean, bn_var, x1, out);
}